// Round 4
// baseline (353.508 us; speedup 1.0000x reference)
//
#include <hip/hip_runtime.h>
#include <hip/hip_bf16.h>
#include <cstdint>

// TT-linear: y[4096,4096] = x[4096,1024] @ W[1024,4096] + bias
// SINGLE persistent kernel (1024 blocks, all co-resident: 4 blocks/CU x 256 CU):
//   phase 1: build W^T bf16 from TT cores (4 (m1,n1,m2,n2) groups per block)
//   device-scope software grid barrier (memset-0 counter + threadfence + agent atomics)
//   phase 2: bf16 MFMA GEMM, 128x128 tile, BK=64; B via global_load_lds w16,
//            A converted f32->bf16 in-register (no xb workspace), XOR-swizzled LDS.

typedef __bf16 bf16x8 __attribute__((ext_vector_type(8)));
typedef float f32x4 __attribute__((ext_vector_type(4)));

__device__ __forceinline__ void g2lds16(const void* g, void* l) {
    __builtin_amdgcn_global_load_lds(
        (const __attribute__((address_space(1))) void*)g,
        (__attribute__((address_space(3))) void*)l,
        16, 0, 0);
}

__global__ __launch_bounds__(256, 4) void tt_fused(
    const float* __restrict__ x,
    const float* __restrict__ c0, const float* __restrict__ c1,
    const float* __restrict__ c2, const float* __restrict__ c3,
    const float* __restrict__ bias,
    __bf16* __restrict__ wt, unsigned* __restrict__ ctr,
    float* __restrict__ C) {
    __shared__ __align__(16) char smem[32768];
    const int t = threadIdx.x;
    const int blk = blockIdx.x;

    // ---------------- phase 1: W^T reconstruction (tiny) -------------------
    {
        float* t12  = (float*)smem;                 // [4][16]
        float* t123 = (float*)(smem + 256);         // [4][512]
        float* c3s  = (float*)(smem + 256 + 8192);  // [512]
        for (int i = t; i < 512; i += 256) c3s[i] = c3[i];
        const int s = t >> 6, lane = t & 63;
        const int g = blk * 4 + s;                  // group 0..4095
        const int m1 = g >> 9, n1 = (g >> 6) & 7, m2 = (g >> 3) & 7, n2 = g & 7;
        __syncthreads();
        if (lane < 16) {
            float sum = 0.f;
            #pragma unroll
            for (int r1 = 0; r1 < 16; ++r1)
                sum += c0[(m1 * 8 + n1) * 16 + r1] * c1[((r1 * 8 + m2) * 8 + n2) * 16 + lane];
            t12[s * 16 + lane] = sum;
        }
        __syncthreads();
        #pragma unroll
        for (int idx = lane; idx < 512; idx += 64) {
            const int m3 = idx >> 7, n3 = (idx >> 4) & 7, r3 = idx & 15;
            float sum = 0.f;
            #pragma unroll
            for (int r2 = 0; r2 < 16; ++r2)
                sum += t12[s * 16 + r2] * c2[((r2 * 4 + m3) * 8 + n3) * 16 + r3];
            t123[s * 512 + (m3 * 8 + n3) * 16 + r3] = sum;
        }
        __syncthreads();
        const int n3 = lane >> 3, n4 = lane & 7;
        const int n = ((n1 * 8 + n2) * 8 + n3) * 8 + n4;
        const int kbase = (m1 * 8 + m2) * 16;
        float v[16];
        #pragma unroll
        for (int e = 0; e < 16; ++e) v[e] = 0.f;
        #pragma unroll
        for (int m3 = 0; m3 < 4; ++m3)
            #pragma unroll
            for (int r3 = 0; r3 < 16; ++r3) {
                const float tv = t123[s * 512 + (m3 * 8 + n3) * 16 + r3];
                #pragma unroll
                for (int m4 = 0; m4 < 4; ++m4)
                    v[m3 * 4 + m4] += tv * c3s[(r3 * 4 + m4) * 8 + n4];
            }
        bf16x8 lo, hi;
        #pragma unroll
        for (int e = 0; e < 8; ++e) { lo[e] = (__bf16)v[e]; hi[e] = (__bf16)v[8 + e]; }
        *(bf16x8*)(wt + (size_t)n * 1024 + kbase)     = lo;
        *(bf16x8*)(wt + (size_t)n * 1024 + kbase + 8) = hi;
    }

    // ---------------- grid barrier (device scope) --------------------------
    __threadfence();          // release our wt stores toward LLC
    __syncthreads();          // all threads' stores drained (vmcnt 0) first
    if (t == 0) {
        __hip_atomic_fetch_add(ctr, 1u, __ATOMIC_ACQ_REL, __HIP_MEMORY_SCOPE_AGENT);
        int spins = 0;
        while (__hip_atomic_load(ctr, __ATOMIC_ACQUIRE, __HIP_MEMORY_SCOPE_AGENT) < 1024u) {
            __builtin_amdgcn_s_sleep(4);
            if (++spins > (1 << 20)) break;   // bounded: no infinite hang
        }
    }
    __syncthreads();

    // ---------------- phase 2: GEMM + bias ---------------------------------
    __bf16* sAp = (__bf16*)smem;            // 16 KB
    __bf16* sBp = (__bf16*)(smem + 16384);  // 16 KB
    const int lane = t & 63, wave = t >> 6;
    const int wm = (wave >> 1) * 64, wn = (wave & 1) * 64;
    const int bm = (blk >> 5) * 128;        // row-major mapping (41 MB FETCH in r1)
    const int bn = (blk & 31) * 128;
    const int l15 = lane & 15, lh = lane >> 4;
    const int swz = l15 & 7;

    f32x4 acc[4][4] = {};

    for (int k0 = 0; k0 < 1024; k0 += 64) {
        __syncthreads();  // prior tile's LDS reads done before overwrite
        #pragma unroll
        for (int i = 0; i < 4; ++i) {       // B: DMA, swizzled source chunk
            const int c = t + i * 256;
            const int r = c >> 3;
            const int gc = (c & 7) ^ (r & 7);
            g2lds16(wt + (size_t)(bn + r) * 1024 + k0 + gc * 8, (char*)sBp + (size_t)c * 16);
        }
        #pragma unroll
        for (int i = 0; i < 4; ++i) {       // A: f32 load + cvt + swizzled ds_write
            const int c = t + i * 256;
            const int r = c >> 3;
            const int lc = c & 7;
            const float4* p = (const float4*)(x + (size_t)(bm + r) * 1024 + k0 + lc * 8);
            float4 a0 = p[0], a1 = p[1];
            bf16x8 o;
            o[0] = (__bf16)a0.x; o[1] = (__bf16)a0.y; o[2] = (__bf16)a0.z; o[3] = (__bf16)a0.w;
            o[4] = (__bf16)a1.x; o[5] = (__bf16)a1.y; o[6] = (__bf16)a1.z; o[7] = (__bf16)a1.w;
            const int pc = lc ^ (r & 7);
            *(bf16x8*)((char*)sAp + (size_t)(r * 8 + pc) * 16) = o;
        }
        asm volatile("s_waitcnt vmcnt(0)" ::: "memory");
        __syncthreads();
        #pragma unroll
        for (int kk = 0; kk < 2; ++kk) {
            const int coff = ((kk * 4 + lh) ^ swz) * 16;
            bf16x8 af[4], bfr[4];
            #pragma unroll
            for (int mi = 0; mi < 4; ++mi)
                af[mi] = *(const bf16x8*)((const char*)sAp + (size_t)(wm + mi * 16 + l15) * 128 + coff);
            #pragma unroll
            for (int ni = 0; ni < 4; ++ni)
                bfr[ni] = *(const bf16x8*)((const char*)sBp + (size_t)(wn + ni * 16 + l15) * 128 + coff);
            #pragma unroll
            for (int mi = 0; mi < 4; ++mi)
                #pragma unroll
                for (int ni = 0; ni < 4; ++ni)
                    acc[mi][ni] = __builtin_amdgcn_mfma_f32_16x16x32_bf16(
                        af[mi], bfr[ni], acc[mi][ni], 0, 0, 0);
        }
    }

    // epilogue: C/D layout col=lane&15, row=(lane>>4)*4+reg (m89-verified)
    #pragma unroll
    for (int ni = 0; ni < 4; ++ni) {
        const int col = bn + wn + ni * 16 + l15;
        const float bv = bias[col];
        #pragma unroll
        for (int mi = 0; mi < 4; ++mi) {
            const int row0 = bm + wm + mi * 16 + lh * 4;
            const f32x4 vv = acc[mi][ni];
            #pragma unroll
            for (int r = 0; r < 4; ++r)
                C[(size_t)(row0 + r) * 4096 + col] = vv[r] + bv;
        }
    }
}

extern "C" void kernel_launch(void* const* d_in, const int* in_sizes, int n_in,
                              void* d_out, int out_size, void* d_ws, size_t ws_size,
                              hipStream_t stream) {
    const float* x    = (const float*)d_in[0];
    const float* c0   = (const float*)d_in[1];
    const float* c1   = (const float*)d_in[2];
    const float* c2   = (const float*)d_in[3];
    const float* c3   = (const float*)d_in[4];
    const float* bias = (const float*)d_in[5];
    float* out = (float*)d_out;

    __bf16* wt = (__bf16*)d_ws;                                  // 8.39 MB
    unsigned* ctr = (unsigned*)((char*)d_ws + (size_t)4096 * 1024 * 2);

    hipMemsetAsync(ctr, 0, 4, stream);   // barrier counter = 0 (ws is poisoned)
    tt_fused<<<1024, 256, 0, stream>>>(x, c0, c1, c2, c3, bias, wt, ctr, out);
}

// Round 5
// 158.835 us; speedup vs baseline: 2.2256x; 2.2256x over previous
//
#include <hip/hip_runtime.h>
#include <hip/hip_bf16.h>
#include <cstdint>

// TT-linear: y[4096,4096] = x[4096,1024] @ W[1024,4096] + bias
// Kernel 1 (prep): fused x->bf16 convert + W^T reconstruction from TT cores.
// Kernel 2 (tt_gemm): bf16 MFMA GEMM, 128x256 block tile, BK=64,
//   4 waves each 64x128 (4x8 acc) -> MFMA/ds_read ratio 2.67 (was 2.0),
//   global_load_lds w16, XOR-swizzled LDS (0 bank conflicts, r3-verified).

typedef __bf16 bf16x8 __attribute__((ext_vector_type(8)));
typedef float f32x4 __attribute__((ext_vector_type(4)));

__device__ __forceinline__ void g2lds16(const void* g, void* l) {
    __builtin_amdgcn_global_load_lds(
        (const __attribute__((address_space(1))) void*)g,
        (__attribute__((address_space(3))) void*)l,
        16, 0, 0);
}

// --------------------------------------------------------------------- prep
// blocks [0,2048): convert x (4096x1024 f32) -> xb bf16, 8 elems/thread
// blocks [2048,3072): build wt[n][k] bf16 (r3-verified)
__global__ __launch_bounds__(256) void prep(
    const float* __restrict__ x, __bf16* __restrict__ xb,
    const float* __restrict__ c0, const float* __restrict__ c1,
    const float* __restrict__ c2, const float* __restrict__ c3,
    __bf16* __restrict__ wt) {
    const int b = blockIdx.x;
    const int t = threadIdx.x;
    if (b < 2048) {
        const int i = (b * 256 + t) * 8;
        float4 a0 = *(const float4*)(x + i);
        float4 a1 = *(const float4*)(x + i + 4);
        bf16x8 o;
        o[0] = (__bf16)a0.x; o[1] = (__bf16)a0.y; o[2] = (__bf16)a0.z; o[3] = (__bf16)a0.w;
        o[4] = (__bf16)a1.x; o[5] = (__bf16)a1.y; o[6] = (__bf16)a1.z; o[7] = (__bf16)a1.w;
        *(bf16x8*)(xb + i) = o;
        return;
    }
    __shared__ float t12[4][16];
    __shared__ float t123[4][512];
    __shared__ float c3s[512];
    #pragma unroll
    for (int i = t; i < 512; i += 256) c3s[i] = c3[i];
    const int s = t >> 6;
    const int lane = t & 63;
    const int g = (b - 2048) * 4 + s;
    const int m1 = g >> 9, n1 = (g >> 6) & 7, m2 = (g >> 3) & 7, n2 = g & 7;
    __syncthreads();
    if (lane < 16) {
        const int r2 = lane;
        float sum = 0.f;
        #pragma unroll
        for (int r1 = 0; r1 < 16; ++r1)
            sum += c0[(m1 * 8 + n1) * 16 + r1] * c1[((r1 * 8 + m2) * 8 + n2) * 16 + r2];
        t12[s][r2] = sum;
    }
    __syncthreads();
    #pragma unroll
    for (int idx = lane; idx < 512; idx += 64) {
        const int m3 = idx >> 7, n3 = (idx >> 4) & 7, r3 = idx & 15;
        float sum = 0.f;
        #pragma unroll
        for (int r2 = 0; r2 < 16; ++r2)
            sum += t12[s][r2] * c2[((r2 * 4 + m3) * 8 + n3) * 16 + r3];
        t123[s][(m3 * 8 + n3) * 16 + r3] = sum;
    }
    __syncthreads();
    const int n3 = lane >> 3, n4 = lane & 7;
    const int n = ((n1 * 8 + n2) * 8 + n3) * 8 + n4;
    const int kbase = (m1 * 8 + m2) * 16;
    float v[16];
    #pragma unroll
    for (int e = 0; e < 16; ++e) v[e] = 0.f;
    #pragma unroll
    for (int m3 = 0; m3 < 4; ++m3) {
        #pragma unroll
        for (int r3 = 0; r3 < 16; ++r3) {
            const float tv = t123[s][(m3 * 8 + n3) * 16 + r3];
            #pragma unroll
            for (int m4 = 0; m4 < 4; ++m4)
                v[m3 * 4 + m4] += tv * c3s[(r3 * 4 + m4) * 8 + n4];
        }
    }
    bf16x8 lo, hi;
    #pragma unroll
    for (int e = 0; e < 8; ++e) { lo[e] = (__bf16)v[e]; hi[e] = (__bf16)v[8 + e]; }
    *(bf16x8*)(wt + (size_t)n * 1024 + kbase)     = lo;
    *(bf16x8*)(wt + (size_t)n * 1024 + kbase + 8) = hi;
}

// -------------------------------------------------------------- GEMM + bias
// C[4096,4096] f32 = A[4096,1024] bf16 @ Bt[4096,1024]^T bf16 + bias
// Block 128x256, BK=64; 4 waves as 2x2, wave tile 64x128 (4x8 of 16x16x32).
// LDS XOR swizzle (physical chunk = logical ^ (row&7)); DMA source swizzled.
__global__ __launch_bounds__(256) void tt_gemm(
    const __bf16* __restrict__ A, const __bf16* __restrict__ B,
    const float* __restrict__ bias, float* __restrict__ C) {
    constexpr int K = 1024, N = 4096;
    __shared__ __bf16 sA[128 * 64];   // 16 KB
    __shared__ __bf16 sB[256 * 64];   // 32 KB
    const int t = threadIdx.x;
    const int lane = t & 63;
    const int wave = t >> 6;
    const int wm = (wave >> 1) * 64;    // 0 or 64
    const int wn = (wave & 1) * 128;    // 0 or 128
    const int bm = (blockIdx.x >> 4) * 128;   // 32 row bands
    const int bn = (blockIdx.x & 15) * 256;   // 16 col bands
    const int l15 = lane & 15, lh = lane >> 4;
    const int swz = l15 & 7;

    f32x4 acc[4][8] = {};

    for (int k0 = 0; k0 < K; k0 += 64) {
        __syncthreads();  // prior tile's ds_reads done before overwrite
        #pragma unroll
        for (int i = 0; i < 4; ++i) {       // A tile: 1024 chunks
            const int c = t + i * 256;
            const int r = c >> 3;
            const int gc = (c & 7) ^ (r & 7);
            g2lds16(A + (size_t)(bm + r) * K + k0 + gc * 8, (char*)sA + (size_t)c * 16);
        }
        #pragma unroll
        for (int i = 0; i < 8; ++i) {       // B tile: 2048 chunks
            const int c = t + i * 256;
            const int r = c >> 3;
            const int gc = (c & 7) ^ (r & 7);
            g2lds16(B + (size_t)(bn + r) * K + k0 + gc * 8, (char*)sB + (size_t)c * 16);
        }
        asm volatile("s_waitcnt vmcnt(0)" ::: "memory");
        __syncthreads();
        #pragma unroll
        for (int kk = 0; kk < 2; ++kk) {
            const int coff = ((kk * 4 + lh) ^ swz) * 16;  // swizzled byte offset
            bf16x8 af[4], bfr[8];
            #pragma unroll
            for (int mi = 0; mi < 4; ++mi)
                af[mi] = *(const bf16x8*)((const char*)sA + (size_t)(wm + mi * 16 + l15) * 128 + coff);
            #pragma unroll
            for (int ni = 0; ni < 8; ++ni)
                bfr[ni] = *(const bf16x8*)((const char*)sB + (size_t)(wn + ni * 16 + l15) * 128 + coff);
            #pragma unroll
            for (int mi = 0; mi < 4; ++mi)
                #pragma unroll
                for (int ni = 0; ni < 8; ++ni)
                    acc[mi][ni] = __builtin_amdgcn_mfma_f32_16x16x32_bf16(
                        af[mi], bfr[ni], acc[mi][ni], 0, 0, 0);
        }
    }

    // epilogue: C/D layout col=lane&15, row=(lane>>4)*4+reg (m89-verified)
    #pragma unroll
    for (int ni = 0; ni < 8; ++ni) {
        const int col = bn + wn + ni * 16 + l15;
        const float bv = bias[col];
        #pragma unroll
        for (int mi = 0; mi < 4; ++mi) {
            const int row0 = bm + wm + mi * 16 + lh * 4;
            const f32x4 v = acc[mi][ni];
            #pragma unroll
            for (int r = 0; r < 4; ++r)
                C[(size_t)(row0 + r) * N + col] = v[r] + bv;
        }
    }
}

extern "C" void kernel_launch(void* const* d_in, const int* in_sizes, int n_in,
                              void* d_out, int out_size, void* d_ws, size_t ws_size,
                              hipStream_t stream) {
    const float* x    = (const float*)d_in[0];
    const float* c0   = (const float*)d_in[1];
    const float* c1   = (const float*)d_in[2];
    const float* c2   = (const float*)d_in[3];
    const float* c3   = (const float*)d_in[4];
    const float* bias = (const float*)d_in[5];
    float* out = (float*)d_out;

    __bf16* xb = (__bf16*)d_ws;                    // 4096*1024 bf16 = 8.39 MB
    __bf16* wt = xb + (size_t)4096 * 1024;         // 4096*1024 bf16 = 8.39 MB

    prep<<<3072, 256, 0, stream>>>(x, xb, c0, c1, c2, c3, wt);
    tt_gemm<<<512, 256, 0, stream>>>(xb, wt, bias, out);
}

// Round 6
// 148.936 us; speedup vs baseline: 2.3736x; 1.0665x over previous
//
#include <hip/hip_runtime.h>
#include <hip/hip_bf16.h>
#include <cstdint>

// TT-linear: y[4096,4096] = x[4096,1024] @ W[1024,4096] + bias
// prep: x->bf16 + W^T reconstruction (known-good from r3/r5).
// tt_gemm: 128x128 tile, BK=32, DOUBLE-BUFFERED LDS (2x16KB, 4 blocks/CU),
//   raw s_barrier (no compiler vmcnt(0) drain) + s_waitcnt vmcnt(4):
//   tile i+1 DMA issued while tile i computes; wait only on tile i's 4 loads.

typedef __bf16 bf16x8 __attribute__((ext_vector_type(8)));
typedef float f32x4 __attribute__((ext_vector_type(4)));

__device__ __forceinline__ void g2lds16(const void* g, void* l) {
    __builtin_amdgcn_global_load_lds(
        (const __attribute__((address_space(1))) void*)g,
        (__attribute__((address_space(3))) void*)l,
        16, 0, 0);
}

// --------------------------------------------------------------------- prep
__global__ __launch_bounds__(256) void prep(
    const float* __restrict__ x, __bf16* __restrict__ xb,
    const float* __restrict__ c0, const float* __restrict__ c1,
    const float* __restrict__ c2, const float* __restrict__ c3,
    __bf16* __restrict__ wt) {
    const int b = blockIdx.x;
    const int t = threadIdx.x;
    if (b < 2048) {
        const int i = (b * 256 + t) * 8;
        float4 a0 = *(const float4*)(x + i);
        float4 a1 = *(const float4*)(x + i + 4);
        bf16x8 o;
        o[0] = (__bf16)a0.x; o[1] = (__bf16)a0.y; o[2] = (__bf16)a0.z; o[3] = (__bf16)a0.w;
        o[4] = (__bf16)a1.x; o[5] = (__bf16)a1.y; o[6] = (__bf16)a1.z; o[7] = (__bf16)a1.w;
        *(bf16x8*)(xb + i) = o;
        return;
    }
    __shared__ float t12[4][16];
    __shared__ float t123[4][512];
    __shared__ float c3s[512];
    #pragma unroll
    for (int i = t; i < 512; i += 256) c3s[i] = c3[i];
    const int s = t >> 6;
    const int lane = t & 63;
    const int g = (b - 2048) * 4 + s;
    const int m1 = g >> 9, n1 = (g >> 6) & 7, m2 = (g >> 3) & 7, n2 = g & 7;
    __syncthreads();
    if (lane < 16) {
        const int r2 = lane;
        float sum = 0.f;
        #pragma unroll
        for (int r1 = 0; r1 < 16; ++r1)
            sum += c0[(m1 * 8 + n1) * 16 + r1] * c1[((r1 * 8 + m2) * 8 + n2) * 16 + r2];
        t12[s][r2] = sum;
    }
    __syncthreads();
    #pragma unroll
    for (int idx = lane; idx < 512; idx += 64) {
        const int m3 = idx >> 7, n3 = (idx >> 4) & 7, r3 = idx & 15;
        float sum = 0.f;
        #pragma unroll
        for (int r2 = 0; r2 < 16; ++r2)
            sum += t12[s][r2] * c2[((r2 * 4 + m3) * 8 + n3) * 16 + r3];
        t123[s][(m3 * 8 + n3) * 16 + r3] = sum;
    }
    __syncthreads();
    const int n3 = lane >> 3, n4 = lane & 7;
    const int n = ((n1 * 8 + n2) * 8 + n3) * 8 + n4;
    const int kbase = (m1 * 8 + m2) * 16;
    float v[16];
    #pragma unroll
    for (int e = 0; e < 16; ++e) v[e] = 0.f;
    #pragma unroll
    for (int m3 = 0; m3 < 4; ++m3) {
        #pragma unroll
        for (int r3 = 0; r3 < 16; ++r3) {
            const float tv = t123[s][(m3 * 8 + n3) * 16 + r3];
            #pragma unroll
            for (int m4 = 0; m4 < 4; ++m4)
                v[m3 * 4 + m4] += tv * c3s[(r3 * 4 + m4) * 8 + n4];
        }
    }
    bf16x8 lo, hi;
    #pragma unroll
    for (int e = 0; e < 8; ++e) { lo[e] = (__bf16)v[e]; hi[e] = (__bf16)v[8 + e]; }
    *(bf16x8*)(wt + (size_t)n * 1024 + kbase)     = lo;
    *(bf16x8*)(wt + (size_t)n * 1024 + kbase + 8) = hi;
}

// -------------------------------------------------------------- GEMM + bias
// C[4096,4096] f32 = A[4096,1024] bf16 @ Bt[4096,1024]^T bf16 + bias
// Block 128x128, BK=32, dbuf. Waves 2x2 of 64x64 (4x4 of 16x16x32 MFMA).
// LDS rows are 64B (4 chunks); physical chunk = logical ^ ((row>>1)&3)
// -> 2 lanes/bank on fragment reads (free). DMA dest = uniform + lane*16.
__global__ __launch_bounds__(256) void tt_gemm(
    const __bf16* __restrict__ A, const __bf16* __restrict__ B,
    const float* __restrict__ bias, float* __restrict__ C) {
    constexpr int K = 1024, N = 4096;
    __shared__ __bf16 sA[2][128 * 32];   // 2 x 8 KB
    __shared__ __bf16 sB[2][128 * 32];   // 2 x 8 KB
    const int t = threadIdx.x;
    const int lane = t & 63;
    const int wave = t >> 6;
    const int wm = (wave >> 1) * 64;
    const int wn = (wave & 1) * 64;
    const int bm = (blockIdx.x >> 5) * 128;   // row-major mapping (41 MB FETCH)
    const int bn = (blockIdx.x & 31) * 128;
    const int l15 = lane & 15, lh = lane >> 4;
    const int coff = ((lh ^ ((l15 >> 1) & 3))) * 16;  // swizzled byte off in 64B row

    // DMA chunk mapping: chunk c (0..511): r=c>>2, pc=c&3, logical gc=pc^((r>>1)&3)
    const int c1 = t, c2 = t + 256;
    const int r1c = c1 >> 2, gc1 = (c1 & 3) ^ ((r1c >> 1) & 3);
    const int r2c = c2 >> 2, gc2 = (c2 & 3) ^ ((r2c >> 1) & 3);
    const __bf16* gA1 = A + (size_t)(bm + r1c) * K + gc1 * 8;
    const __bf16* gA2 = A + (size_t)(bm + r2c) * K + gc2 * 8;
    const __bf16* gB1 = B + (size_t)(bn + r1c) * K + gc1 * 8;
    const __bf16* gB2 = B + (size_t)(bn + r2c) * K + gc2 * 8;

    f32x4 acc[4][4] = {};

    // prologue: tile 0 -> buf 0
    g2lds16(gA1, (char*)sA[0] + (size_t)c1 * 16);
    g2lds16(gA2, (char*)sA[0] + (size_t)c2 * 16);
    g2lds16(gB1, (char*)sB[0] + (size_t)c1 * 16);
    g2lds16(gB2, (char*)sB[0] + (size_t)c2 * 16);

    for (int i = 0; i < 32; ++i) {
        const int p = i & 1;
        // all waves done reading buf p^1 (computed at i-1) before overwrite
        asm volatile("s_barrier" ::: "memory");
        if (i < 31) {
            const int k1 = (i + 1) * 32;
            g2lds16(gA1 + k1, (char*)sA[p ^ 1] + (size_t)c1 * 16);
            g2lds16(gA2 + k1, (char*)sA[p ^ 1] + (size_t)c2 * 16);
            g2lds16(gB1 + k1, (char*)sB[p ^ 1] + (size_t)c1 * 16);
            g2lds16(gB2 + k1, (char*)sB[p ^ 1] + (size_t)c2 * 16);
            asm volatile("s_waitcnt vmcnt(4)" ::: "memory");  // tile i's 4 done
        } else {
            asm volatile("s_waitcnt vmcnt(0)" ::: "memory");
        }
        asm volatile("s_barrier" ::: "memory");  // tile i visible to all waves
        bf16x8 af[4], bfr[4];
        #pragma unroll
        for (int mi = 0; mi < 4; ++mi)
            af[mi] = *(const bf16x8*)((const char*)sA[p] + (size_t)(wm + mi * 16 + l15) * 64 + coff);
        #pragma unroll
        for (int ni = 0; ni < 4; ++ni)
            bfr[ni] = *(const bf16x8*)((const char*)sB[p] + (size_t)(wn + ni * 16 + l15) * 64 + coff);
        #pragma unroll
        for (int mi = 0; mi < 4; ++mi)
            #pragma unroll
            for (int ni = 0; ni < 4; ++ni)
                acc[mi][ni] = __builtin_amdgcn_mfma_f32_16x16x32_bf16(
                    af[mi], bfr[ni], acc[mi][ni], 0, 0, 0);
    }

    // epilogue: C/D layout col=lane&15, row=(lane>>4)*4+reg (m89-verified)
    #pragma unroll
    for (int ni = 0; ni < 4; ++ni) {
        const int col = bn + wn + ni * 16 + l15;
        const float bv = bias[col];
        #pragma unroll
        for (int mi = 0; mi < 4; ++mi) {
            const int row0 = bm + wm + mi * 16 + lh * 4;
            const f32x4 v = acc[mi][ni];
            #pragma unroll
            for (int r = 0; r < 4; ++r)
                C[(size_t)(row0 + r) * N + col] = v[r] + bv;
        }
    }
}

extern "C" void kernel_launch(void* const* d_in, const int* in_sizes, int n_in,
                              void* d_out, int out_size, void* d_ws, size_t ws_size,
                              hipStream_t stream) {
    const float* x    = (const float*)d_in[0];
    const float* c0   = (const float*)d_in[1];
    const float* c1   = (const float*)d_in[2];
    const float* c2   = (const float*)d_in[3];
    const float* c3   = (const float*)d_in[4];
    const float* bias = (const float*)d_in[5];
    float* out = (float*)d_out;

    __bf16* xb = (__bf16*)d_ws;                    // 4096*1024 bf16 = 8.39 MB
    __bf16* wt = xb + (size_t)4096 * 1024;         // 4096*1024 bf16 = 8.39 MB

    prep<<<3072, 256, 0, stream>>>(x, xb, c0, c1, c2, c3, wt);
    tt_gemm<<<1024, 256, 0, stream>>>(xb, wt, bias, out);
}